// Round 1
// baseline (176.254 us; speedup 1.0000x reference)
//
#include <hip/hip_runtime.h>
#include <hip/hip_bf16.h>
#include <math.h>

#define NROWS 8192
#define DIM   768
#define BM    128
#define BK    64
#define NT    (NROWS / BM)   // 64 tiles per dim

typedef __attribute__((ext_vector_type(4))) float  f32x4;
typedef __attribute__((ext_vector_type(8))) __bf16 bf16x8;
typedef __attribute__((ext_vector_type(4))) __bf16 bf16x4;

// ---------------------------------------------------------------------------
// Kernel 1: row squared-norms (f32, exact) + init per-row min-d2 to +inf
// one wave per row; 4 rows per 256-thread block
// ---------------------------------------------------------------------------
__global__ __launch_bounds__(256) void koleo_prep(const float* __restrict__ X,
                                                  float* __restrict__ sq,
                                                  unsigned int* __restrict__ minbits) {
  const int row  = blockIdx.x * 4 + (threadIdx.x >> 6);
  const int lane = threadIdx.x & 63;
  const float* xr = X + (size_t)row * DIM;
  float s = 0.f;
#pragma unroll
  for (int i = 0; i < 3; ++i) {              // 768 = 3 * 64 lanes * 4 floats
    f32x4 v = *(const f32x4*)(xr + lane * 4 + i * 256);
    s += v.x * v.x + v.y * v.y + v.z * v.z + v.w * v.w;
  }
#pragma unroll
  for (int m = 32; m >= 1; m >>= 1) s += __shfl_xor(s, m, 64);
  if (lane == 0) {
    sq[row]      = s;
    minbits[row] = 0x7F800000u;              // +inf
  }
}

// ---------------------------------------------------------------------------
// Kernel 2: upper-triangular 128x128 Gram tiles via bf16 MFMA; fused epilogue
// computes d2 = sq_i + sq_j - 2*g, masks diagonal, row-min AND col-min,
// atomicMin (uint bits, valid for non-negative floats) into ws.
// ---------------------------------------------------------------------------
__global__ __launch_bounds__(256) void koleo_tile(const float* __restrict__ X,
                                                  const float* __restrict__ sq,
                                                  unsigned int* __restrict__ minbits) {
  __shared__ __align__(16) char sA[BM * BK * 2];   // 16 KB bf16 tile (swizzled)
  __shared__ __align__(16) char sB[BM * BK * 2];

  // linear blockIdx -> upper-triangular (ti, tj), tj >= ti
  int rem = blockIdx.x, ti = 0, rowlen = NT;
  while (rem >= rowlen) { rem -= rowlen; ++ti; --rowlen; }
  const int tj = ti + rem;
  const int i0 = ti * BM, j0 = tj * BM;

  const int tid  = threadIdx.x;
  const int lane = tid & 63;
  const int wave = tid >> 6;
  const int wr   = wave >> 1;   // 0..1 : row half of 128x128
  const int wc   = wave & 1;    // 0..1 : col half

  f32x4 acc[4][4] = {};         // 64x64 per wave: 4x4 fragments of 16x16

  for (int k0 = 0; k0 < DIM; k0 += BK) {
    __syncthreads();            // protect LDS from previous iteration's readers
    // stage A (rows i0..) and B (rows j0..): 8 float4 per thread per tile,
    // f32 -> bf16 convert, XOR-swizzled LDS write (byte ^= (row&7)<<4)
#pragma unroll
    for (int it = 0; it < 8; ++it) {
      const int idx = tid + it * 256;       // 0..2047
      const int r   = idx >> 4;             // tile row 0..127
      const int c4  = idx & 15;             // float4 col 0..15 (k = c4*4)
      f32x4 va = *(const f32x4*)(X + (size_t)(i0 + r) * DIM + k0 + c4 * 4);
      f32x4 vb = *(const f32x4*)(X + (size_t)(j0 + r) * DIM + k0 + c4 * 4);
      bf16x4 ha, hb;
      ha[0] = (__bf16)va.x; ha[1] = (__bf16)va.y;
      ha[2] = (__bf16)va.z; ha[3] = (__bf16)va.w;
      hb[0] = (__bf16)vb.x; hb[1] = (__bf16)vb.y;
      hb[2] = (__bf16)vb.z; hb[3] = (__bf16)vb.w;
      int off = r * 128 + c4 * 8;           // bytes; row stride = 64 bf16 = 128B
      off ^= (r & 7) << 4;                  // bank-conflict swizzle
      *(bf16x4*)(sA + off) = ha;
      *(bf16x4*)(sB + off) = hb;
    }
    __syncthreads();

#pragma unroll
    for (int ks = 0; ks < 2; ++ks) {        // two K=32 MFMA steps per BK=64
      bf16x8 af[4], bfr[4];
#pragma unroll
      for (int m = 0; m < 4; ++m) {
        const int ra = wr * 64 + m * 16 + (lane & 15);
        int offa = ra * 128 + ks * 64 + (lane >> 4) * 16;
        offa ^= (ra & 7) << 4;
        af[m] = *(const bf16x8*)(sA + offa);
        const int rb = wc * 64 + m * 16 + (lane & 15);
        int offb = rb * 128 + ks * 64 + (lane >> 4) * 16;
        offb ^= (rb & 7) << 4;
        bfr[m] = *(const bf16x8*)(sB + offb);
      }
#pragma unroll
      for (int m = 0; m < 4; ++m)
#pragma unroll
        for (int n = 0; n < 4; ++n)
          acc[m][n] = __builtin_amdgcn_mfma_f32_16x16x32_bf16(af[m], bfr[n], acc[m][n], 0, 0, 0);
    }
  }

  // ---- epilogue: d2, diagonal mask, row-min + col-min, atomicMin ----------
  // C/D layout (m89): col = lane&15, row = (lane>>4)*4 + reg
  const int cg = lane >> 4;     // row group 0..3
  const int cl = lane & 15;     // col 0..15
  float sqj[4], colmin[4];
#pragma unroll
  for (int n = 0; n < 4; ++n) {
    sqj[n]    = sq[j0 + wc * 64 + n * 16 + cl];
    colmin[n] = INFINITY;
  }
#pragma unroll
  for (int m = 0; m < 4; ++m) {
#pragma unroll
    for (int r = 0; r < 4; ++r) {
      const int gi = i0 + wr * 64 + m * 16 + cg * 4 + r;
      const float si = sq[gi];
      float rowmin = INFINITY;
#pragma unroll
      for (int n = 0; n < 4; ++n) {
        const int gj = j0 + wc * 64 + n * 16 + cl;
        float d2 = si + sqj[n] - 2.0f * acc[m][n][r];
        d2 = fmaxf(d2, 0.0f);
        if (gi == gj) d2 = INFINITY;        // exclude self (diagonal tiles)
        rowmin    = fminf(rowmin, d2);
        colmin[n] = fminf(colmin[n], d2);
      }
      // reduce across the 16 lanes sharing this row (cl varies)
      rowmin = fminf(rowmin, __shfl_xor(rowmin, 1, 64));
      rowmin = fminf(rowmin, __shfl_xor(rowmin, 2, 64));
      rowmin = fminf(rowmin, __shfl_xor(rowmin, 4, 64));
      rowmin = fminf(rowmin, __shfl_xor(rowmin, 8, 64));
      if (cl == 0)
        atomicMin(minbits + gi, __float_as_uint(rowmin));
    }
  }
  if (ti != tj) {               // symmetric update: this tile's cols are rows j
#pragma unroll
    for (int n = 0; n < 4; ++n) {
      float cm = colmin[n];
      cm = fminf(cm, __shfl_xor(cm, 16, 64));
      cm = fminf(cm, __shfl_xor(cm, 32, 64));
      if (cg == 0)
        atomicMin(minbits + j0 + wc * 64 + n * 16 + cl, __float_as_uint(cm));
    }
  }
}

// ---------------------------------------------------------------------------
// Kernel 3: loss = -mean(log(sqrt(min_d2) + eps)), single block
// ---------------------------------------------------------------------------
__global__ __launch_bounds__(1024) void koleo_final(const unsigned int* __restrict__ minbits,
                                                    float* __restrict__ out) {
  __shared__ float wsum[16];
  float s = 0.f;
  for (int i = threadIdx.x; i < NROWS; i += 1024) {
    float d2 = __uint_as_float(minbits[i]);
    s += logf(sqrtf(d2) + 1e-8f);
  }
#pragma unroll
  for (int m = 32; m >= 1; m >>= 1) s += __shfl_xor(s, m, 64);
  const int wv = threadIdx.x >> 6, ln = threadIdx.x & 63;
  if (ln == 0) wsum[wv] = s;
  __syncthreads();
  if (wv == 0) {
    float t = (ln < 16) ? wsum[ln] : 0.f;
#pragma unroll
    for (int m = 8; m >= 1; m >>= 1) t += __shfl_xor(t, m, 64);
    if (ln == 0) out[0] = -t / (float)NROWS;
  }
}

// ---------------------------------------------------------------------------
extern "C" void kernel_launch(void* const* d_in, const int* in_sizes, int n_in,
                              void* d_out, int out_size, void* d_ws, size_t ws_size,
                              hipStream_t stream) {
  const float* X = (const float*)d_in[0];
  float* out = (float*)d_out;
  unsigned int* minbits = (unsigned int*)d_ws;                       // 32 KB
  float* sq = (float*)((char*)d_ws + NROWS * sizeof(unsigned int));  // 32 KB

  koleo_prep<<<NROWS / 4, 256, 0, stream>>>(X, sq, minbits);
  koleo_tile<<<NT * (NT + 1) / 2, 256, 0, stream>>>(X, sq, minbits);
  koleo_final<<<1, 1024, 0, stream>>>(minbits, out);
}

// Round 2
// 126.620 us; speedup vs baseline: 1.3920x; 1.3920x over previous
//
#include <hip/hip_runtime.h>
#include <hip/hip_bf16.h>
#include <math.h>

#define NROWS 8192
#define DIM   768
#define BM    128
#define BK    64
#define NT    (NROWS / BM)       // 64 row-blocks
#define NKB   (DIM / BK)         // 12 k-blocks
#define CHUNK (BM * BK * 2)      // 16384 bytes per bf16 tile chunk

typedef __attribute__((ext_vector_type(4))) float  f32x4;
typedef __attribute__((ext_vector_type(8))) __bf16 bf16x8;
typedef __attribute__((ext_vector_type(4))) __bf16 bf16x4;

__device__ __forceinline__ void gload_lds16(const void* g, void* l) {
  __builtin_amdgcn_global_load_lds(
      (const __attribute__((address_space(1))) void*)g,
      (__attribute__((address_space(3))) void*)l, 16, 0, 0);
}

// ---------------------------------------------------------------------------
// Kernel A (fast path): fused convert+prep.
// One wave per row: f32 row -> sq-norm (f32 exact, shfl-reduce) AND bf16
// conversion written into tile-chunk layout with the LDS swizzle PRE-APPLIED:
//   chunk = (row/128)*12 + col/64 ; within chunk, element (r=row%128, c=col%64)
//   lives at byte (r*128 + c*2) ^ ((r&7)<<4).
// 8-byte stores never straddle a 16B granule, so the XOR (bits 4..6) is safe.
// ---------------------------------------------------------------------------
__global__ __launch_bounds__(256) void koleo_convert(const float* __restrict__ X,
                                                     float* __restrict__ sq,
                                                     unsigned int* __restrict__ minbits,
                                                     char* __restrict__ xbf) {
  const int row  = blockIdx.x * 4 + (threadIdx.x >> 6);
  const int lane = threadIdx.x & 63;
  const int rb = row >> 7, r = row & 127;
  const float* xr = X + (size_t)row * DIM;
  float s = 0.f;
#pragma unroll
  for (int i = 0; i < 3; ++i) {            // 768 = 3 * 64 lanes * 4 floats
    const int c0 = lane * 4 + i * 256;     // global col
    f32x4 v = *(const f32x4*)(xr + c0);
    s += v.x * v.x + v.y * v.y + v.z * v.z + v.w * v.w;
    bf16x4 h;
    h[0] = (__bf16)v.x; h[1] = (__bf16)v.y; h[2] = (__bf16)v.z; h[3] = (__bf16)v.w;
    const int kb = c0 >> 6;                // chunk col-block
    const int c  = c0 & 63;                // col within chunk
    const int off = (r * 128 + c * 2) ^ ((r & 7) << 4);
    *(bf16x4*)(xbf + (size_t)(rb * NKB + kb) * CHUNK + off) = h;
  }
#pragma unroll
  for (int m = 32; m >= 1; m >>= 1) s += __shfl_xor(s, m, 64);
  if (lane == 0) {
    sq[row]      = s;
    minbits[row] = 0x7F800000u;            // +inf
  }
}

// ---------------------------------------------------------------------------
// Kernel B (fast path): upper-triangular 128x128 Gram tiles.
// Staging = pure linear 16KB global_load_lds DMA from the pre-swizzled chunks
// (zero VALU, zero cvt). 2-barrier m97-style loop. Fused min-epilogue.
// ---------------------------------------------------------------------------
__global__ __launch_bounds__(256) void koleo_tile(const char* __restrict__ xbf,
                                                  const float* __restrict__ sq,
                                                  unsigned int* __restrict__ minbits) {
  __shared__ __align__(16) char sA[CHUNK];
  __shared__ __align__(16) char sB[CHUNK];

  // linear blockIdx -> upper-triangular (ti, tj), tj >= ti
  int rem = blockIdx.x, ti = 0, rowlen = NT;
  while (rem >= rowlen) { rem -= rowlen; ++ti; --rowlen; }
  const int tj = ti + rem;
  const int i0 = ti * BM, j0 = tj * BM;

  const int tid  = threadIdx.x;
  const int lane = tid & 63;
  const int wave = tid >> 6;
  const int wr   = wave >> 1;   // 0..1 : row half
  const int wc   = wave & 1;    // 0..1 : col half

  const char* gA = xbf + (size_t)ti * NKB * CHUNK;
  const char* gB = xbf + (size_t)tj * NKB * CHUNK;
  const int stg = wave * 4096 + lane * 16;   // per-lane global offset base

  f32x4 acc[4][4] = {};

  for (int kb = 0; kb < NKB; ++kb) {
    __syncthreads();                         // readers done with LDS
#pragma unroll
    for (int t = 0; t < 4; ++t) {            // 4 KB per wave per tile
      gload_lds16(gA + stg + t * 1024, sA + wave * 4096 + t * 1024);
      gload_lds16(gB + stg + t * 1024, sB + wave * 4096 + t * 1024);
    }
    __syncthreads();                         // implicit vmcnt(0) drain

#pragma unroll
    for (int ks = 0; ks < 2; ++ks) {         // two K=32 steps per BK=64
      bf16x8 af[4], bfr[4];
#pragma unroll
      for (int m = 0; m < 4; ++m) {
        const int ra = wr * 64 + m * 16 + (lane & 15);
        af[m]  = *(const bf16x8*)(sA + ((ra * 128 + ks * 64 + (lane >> 4) * 16) ^ ((ra & 7) << 4)));
        const int rb2 = wc * 64 + m * 16 + (lane & 15);
        bfr[m] = *(const bf16x8*)(sB + ((rb2 * 128 + ks * 64 + (lane >> 4) * 16) ^ ((rb2 & 7) << 4)));
      }
#pragma unroll
      for (int m = 0; m < 4; ++m)
#pragma unroll
        for (int n = 0; n < 4; ++n)
          acc[m][n] = __builtin_amdgcn_mfma_f32_16x16x32_bf16(af[m], bfr[n], acc[m][n], 0, 0, 0);
    }
    gA += CHUNK; gB += CHUNK;
  }

  // ---- epilogue: d2, diagonal mask, row-min + col-min, atomicMin ----------
  // C/D layout (m89): col = lane&15, row = (lane>>4)*4 + reg
  const int cg = lane >> 4;
  const int cl = lane & 15;
  float sqj[4], colmin[4];
#pragma unroll
  for (int n = 0; n < 4; ++n) {
    sqj[n]    = sq[j0 + wc * 64 + n * 16 + cl];
    colmin[n] = INFINITY;
  }
#pragma unroll
  for (int m = 0; m < 4; ++m) {
#pragma unroll
    for (int r = 0; r < 4; ++r) {
      const int gi = i0 + wr * 64 + m * 16 + cg * 4 + r;
      const float si = sq[gi];
      float rowmin = INFINITY;
#pragma unroll
      for (int n = 0; n < 4; ++n) {
        const int gj = j0 + wc * 64 + n * 16 + cl;
        float d2 = si + sqj[n] - 2.0f * acc[m][n][r];
        d2 = fmaxf(d2, 0.0f);
        if (gi == gj) d2 = INFINITY;
        rowmin    = fminf(rowmin, d2);
        colmin[n] = fminf(colmin[n], d2);
      }
      rowmin = fminf(rowmin, __shfl_xor(rowmin, 1, 64));
      rowmin = fminf(rowmin, __shfl_xor(rowmin, 2, 64));
      rowmin = fminf(rowmin, __shfl_xor(rowmin, 4, 64));
      rowmin = fminf(rowmin, __shfl_xor(rowmin, 8, 64));
      if (cl == 0)
        atomicMin(minbits + gi, __float_as_uint(rowmin));
    }
  }
  if (ti != tj) {
#pragma unroll
    for (int n = 0; n < 4; ++n) {
      float cm = colmin[n];
      cm = fminf(cm, __shfl_xor(cm, 16, 64));
      cm = fminf(cm, __shfl_xor(cm, 32, 64));
      if (cg == 0)
        atomicMin(minbits + j0 + wc * 64 + n * 16 + cl, __float_as_uint(cm));
    }
  }
}

// ---------------------------------------------------------------------------
// Fallback (ws too small): R1 kernels — f32 load + in-loop cvt staging.
// ---------------------------------------------------------------------------
__global__ __launch_bounds__(256) void koleo_prep_fb(const float* __restrict__ X,
                                                     float* __restrict__ sq,
                                                     unsigned int* __restrict__ minbits) {
  const int row  = blockIdx.x * 4 + (threadIdx.x >> 6);
  const int lane = threadIdx.x & 63;
  const float* xr = X + (size_t)row * DIM;
  float s = 0.f;
#pragma unroll
  for (int i = 0; i < 3; ++i) {
    f32x4 v = *(const f32x4*)(xr + lane * 4 + i * 256);
    s += v.x * v.x + v.y * v.y + v.z * v.z + v.w * v.w;
  }
#pragma unroll
  for (int m = 32; m >= 1; m >>= 1) s += __shfl_xor(s, m, 64);
  if (lane == 0) { sq[row] = s; minbits[row] = 0x7F800000u; }
}

__global__ __launch_bounds__(256) void koleo_tile_fb(const float* __restrict__ X,
                                                     const float* __restrict__ sq,
                                                     unsigned int* __restrict__ minbits) {
  __shared__ __align__(16) char sA[CHUNK];
  __shared__ __align__(16) char sB[CHUNK];
  int rem = blockIdx.x, ti = 0, rowlen = NT;
  while (rem >= rowlen) { rem -= rowlen; ++ti; --rowlen; }
  const int tj = ti + rem;
  const int i0 = ti * BM, j0 = tj * BM;
  const int tid = threadIdx.x, lane = tid & 63, wave = tid >> 6;
  const int wr = wave >> 1, wc = wave & 1;
  f32x4 acc[4][4] = {};
  for (int k0 = 0; k0 < DIM; k0 += BK) {
    __syncthreads();
#pragma unroll
    for (int it = 0; it < 8; ++it) {
      const int idx = tid + it * 256;
      const int r = idx >> 4, c4 = idx & 15;
      f32x4 va = *(const f32x4*)(X + (size_t)(i0 + r) * DIM + k0 + c4 * 4);
      f32x4 vb = *(const f32x4*)(X + (size_t)(j0 + r) * DIM + k0 + c4 * 4);
      bf16x4 ha, hb;
      ha[0] = (__bf16)va.x; ha[1] = (__bf16)va.y; ha[2] = (__bf16)va.z; ha[3] = (__bf16)va.w;
      hb[0] = (__bf16)vb.x; hb[1] = (__bf16)vb.y; hb[2] = (__bf16)vb.z; hb[3] = (__bf16)vb.w;
      int off = (r * 128 + c4 * 8) ^ ((r & 7) << 4);
      *(bf16x4*)(sA + off) = ha;
      *(bf16x4*)(sB + off) = hb;
    }
    __syncthreads();
#pragma unroll
    for (int ks = 0; ks < 2; ++ks) {
      bf16x8 af[4], bfr[4];
#pragma unroll
      for (int m = 0; m < 4; ++m) {
        const int ra = wr * 64 + m * 16 + (lane & 15);
        af[m]  = *(const bf16x8*)(sA + ((ra * 128 + ks * 64 + (lane >> 4) * 16) ^ ((ra & 7) << 4)));
        const int rb2 = wc * 64 + m * 16 + (lane & 15);
        bfr[m] = *(const bf16x8*)(sB + ((rb2 * 128 + ks * 64 + (lane >> 4) * 16) ^ ((rb2 & 7) << 4)));
      }
#pragma unroll
      for (int m = 0; m < 4; ++m)
#pragma unroll
        for (int n = 0; n < 4; ++n)
          acc[m][n] = __builtin_amdgcn_mfma_f32_16x16x32_bf16(af[m], bfr[n], acc[m][n], 0, 0, 0);
    }
  }
  const int cg = lane >> 4, cl = lane & 15;
  float sqj[4], colmin[4];
#pragma unroll
  for (int n = 0; n < 4; ++n) { sqj[n] = sq[j0 + wc * 64 + n * 16 + cl]; colmin[n] = INFINITY; }
#pragma unroll
  for (int m = 0; m < 4; ++m) {
#pragma unroll
    for (int r = 0; r < 4; ++r) {
      const int gi = i0 + wr * 64 + m * 16 + cg * 4 + r;
      const float si = sq[gi];
      float rowmin = INFINITY;
#pragma unroll
      for (int n = 0; n < 4; ++n) {
        const int gj = j0 + wc * 64 + n * 16 + cl;
        float d2 = si + sqj[n] - 2.0f * acc[m][n][r];
        d2 = fmaxf(d2, 0.0f);
        if (gi == gj) d2 = INFINITY;
        rowmin = fminf(rowmin, d2);
        colmin[n] = fminf(colmin[n], d2);
      }
      rowmin = fminf(rowmin, __shfl_xor(rowmin, 1, 64));
      rowmin = fminf(rowmin, __shfl_xor(rowmin, 2, 64));
      rowmin = fminf(rowmin, __shfl_xor(rowmin, 4, 64));
      rowmin = fminf(rowmin, __shfl_xor(rowmin, 8, 64));
      if (cl == 0) atomicMin(minbits + gi, __float_as_uint(rowmin));
    }
  }
  if (ti != tj) {
#pragma unroll
    for (int n = 0; n < 4; ++n) {
      float cm = colmin[n];
      cm = fminf(cm, __shfl_xor(cm, 16, 64));
      cm = fminf(cm, __shfl_xor(cm, 32, 64));
      if (cg == 0) atomicMin(minbits + j0 + wc * 64 + n * 16 + cl, __float_as_uint(cm));
    }
  }
}

// ---------------------------------------------------------------------------
// Final: loss = -mean(log(sqrt(min_d2) + eps)), single block
// ---------------------------------------------------------------------------
__global__ __launch_bounds__(1024) void koleo_final(const unsigned int* __restrict__ minbits,
                                                    float* __restrict__ out) {
  __shared__ float wsum[16];
  float s = 0.f;
  for (int i = threadIdx.x; i < NROWS; i += 1024) {
    float d2 = __uint_as_float(minbits[i]);
    s += logf(sqrtf(d2) + 1e-8f);
  }
#pragma unroll
  for (int m = 32; m >= 1; m >>= 1) s += __shfl_xor(s, m, 64);
  const int wv = threadIdx.x >> 6, ln = threadIdx.x & 63;
  if (ln == 0) wsum[wv] = s;
  __syncthreads();
  if (wv == 0) {
    float t = (ln < 16) ? wsum[ln] : 0.f;
#pragma unroll
    for (int m = 8; m >= 1; m >>= 1) t += __shfl_xor(t, m, 64);
    if (ln == 0) out[0] = -t / (float)NROWS;
  }
}

// ---------------------------------------------------------------------------
extern "C" void kernel_launch(void* const* d_in, const int* in_sizes, int n_in,
                              void* d_out, int out_size, void* d_ws, size_t ws_size,
                              hipStream_t stream) {
  const float* X = (const float*)d_in[0];
  float* out = (float*)d_out;
  unsigned int* minbits = (unsigned int*)d_ws;                       // 32 KB
  float* sq = (float*)((char*)d_ws + NROWS * sizeof(unsigned int));  // 32 KB
  char* xbf = (char*)d_ws + 65536;                                   // 12.58 MB

  const size_t need = 65536 + (size_t)NT * NKB * CHUNK;
  if (ws_size >= need) {
    koleo_convert<<<NROWS / 4, 256, 0, stream>>>(X, sq, minbits, xbf);
    koleo_tile<<<NT * (NT + 1) / 2, 256, 0, stream>>>(xbf, sq, minbits);
  } else {
    koleo_prep_fb<<<NROWS / 4, 256, 0, stream>>>(X, sq, minbits);
    koleo_tile_fb<<<NT * (NT + 1) / 2, 256, 0, stream>>>(X, sq, minbits);
  }
  koleo_final<<<1, 1024, 0, stream>>>(minbits, out);
}